// Round 12
// baseline (2928.998 us; speedup 1.0000x reference)
//
#include <hip/hip_runtime.h>

#define HH   100      // hidden
#define G4   400      // 4*H
#define BB   256      // batch
#define CC   9        // input channels
#define TT   1024     // timesteps
#define NCLS 6        // num classes

__device__ __forceinline__ float sigm(float x) {
    return __fdividef(1.0f, 1.0f + __expf(-x));
}
__device__ __forceinline__ float tanh_fast(float x) {
    return 2.0f * sigm(2.0f * x) - 1.0f;
}
// wave-wide broadcast of lane l's value via readlane -> SGPR.
// REQUIRES: v computed by ALL 64 lanes of the wave (no divergence upstream).
__device__ __forceinline__ float bcast(float v, int l) {
    return __int_as_float(__builtin_amdgcn_readlane(__float_as_int(v), l));
}
// launder a pointer so weight loads are NOT rematerializable (forces the
// allocator to keep the loaded array resident -- R10-L2 evidence: 112 VGPRs)
__device__ __forceinline__ const float* launder(const float* p) {
    asm volatile("" : "+v"(p));
    return p;
}

// ---- xproj: pre[b][t][r] = b1[r] + sum_c W_ih1[r][c] * x[b][c][t] ----
__global__ __launch_bounds__(512, 2)
void xproj(const float* __restrict__ x,      // [B,C,T]
           const float* __restrict__ W_ih,   // [400,9]
           const float* __restrict__ bias,   // [400]
           float* __restrict__ pre,          // [B][chSteps][400]
           int tbase, int chSteps)
{
    const int b    = blockIdx.x;
    const int tile = blockIdx.y;              // 64 steps per tile
    const int tid  = threadIdx.x;
    const int t0g  = tbase + tile * 64;

    __shared__ float xt[CC][64];
    for (int i = tid; i < CC * 64; i += 512) {
        int c = i >> 6, k = i & 63;
        xt[c][k] = x[(size_t)b * CC * TT + c * TT + t0g + k];
    }
    __syncthreads();

    if (tid < G4) {
        const float* w = launder(W_ih + tid * CC);
        float wv[CC];
        #pragma unroll
        for (int c = 0; c < CC; ++c) wv[c] = w[c];
        const float bg = bias[tid];
        float* po = pre + ((size_t)b * chSteps + tile * 64) * G4 + tid;
        #pragma unroll 1
        for (int k = 0; k < 64; ++k) {
            float a = bg;
            #pragma unroll
            for (int c = 0; c < CC; ++c) a += wv[c] * xt[c][k];  // uniform LDS bcast
            po[(size_t)k * G4] = a;
        }
    }
}

// ---- hproj: pre[b][t][r] = b2[r] + sum_j W_ih2[r][j] * h1[b][t][j] ----
__global__ __launch_bounds__(512, 2)
void hproj(const float* __restrict__ h1,     // [B,T,H]
           const float* __restrict__ W_ih,   // [400,100]
           const float* __restrict__ bias,   // [400]
           float* __restrict__ pre,          // [B][chSteps][400]
           int tbase, int chSteps)
{
    const int b    = blockIdx.x;
    const int tile = blockIdx.y;
    const int tid  = threadIdx.x;
    const int lane = tid & 63;
    const int t0g  = tbase + tile * 64;

    __shared__ float ht[64][128];   // h1 tile, padded rows (32 KB)
    for (int i = tid; i < 64 * 25; i += 512) {
        int r = i / 25, c = i - r * 25;
        *((float4*)&ht[r][4 * c]) =
            *((const float4*)(h1 + ((size_t)b * TT + t0g + r) * HH) + c);
    }
    __syncthreads();

    if (tid < 448) {    // wave-uniform: waves 0..6 all-lane active
        const int row = (tid < G4) ? tid : 0;
        const float* w = launder(W_ih + row * HH);
        float wv[HH];
        #pragma unroll
        for (int j = 0; j < HH / 4; ++j)
            *(float4*)&wv[4 * j] = ((const float4*)w)[j];
        const float bg = bias[row];
        float* po = pre + ((size_t)b * chSteps + tile * 64) * G4 + row;
        #pragma unroll 1
        for (int k = 0; k < 64; ++k) {
            float va = ht[k][lane];
            float vb = ht[k][64 + lane];   // lanes >= 36: in-bounds pad, unused
            asm volatile("" : "+v"(va), "+v"(vb));
            float a0 = bg, a1 = 0.f;
            #pragma unroll
            for (int j = 0; j < 64; ++j) {
                float s = bcast(va, j);
                if (j & 1) a1 += s * wv[j]; else a0 += s * wv[j];
            }
            #pragma unroll
            for (int j = 0; j < 36; ++j) {
                float s = bcast(vb, j);
                if (j & 1) a1 += s * wv[64 + j]; else a0 += s * wv[64 + j];
            }
            if (tid < G4) po[(size_t)k * G4] = a0 + a1;
        }
    }
}

// ---- recurrence (both layers): gates = pre[t] + W_hh . h ----
// writeH: layer1 writes h1[b][t][:]; doFC: layer2 last chunk runs the FC.
__global__ __launch_bounds__(512, 2)
void lstm_rec(const float* __restrict__ pre,  // [B][chSteps][400]
              const float* __restrict__ h0,
              const float* __restrict__ c0,
              const float* __restrict__ W_hh, // [400,100]
              float* __restrict__ h1out,      // [B,T,H] or nullptr
              float* __restrict__ st,         // [B][200] persisted h,c
              const float* __restrict__ W_fc, // [6,100] (layer2)
              const float* __restrict__ b_fc,
              float* __restrict__ out,        // [B,NC]
              int tbase, int chSteps, int flags) // 1=writeH, 2=doFC
{
    const int b    = blockIdx.x;
    const int tid  = threadIdx.x;
    const int lane = tid & 63;
    const bool first = (tbase == 0);

    __shared__ float hb[128];
    __shared__ float gates[448];

    if (tid < 128)
        hb[tid] = (tid < HH)
                    ? (first ? h0[b * HH + tid] : st[b * 200 + tid])
                    : 0.0f;
    float c_reg = (tid < HH)
                    ? (first ? c0[b * HH + tid] : st[b * 200 + HH + tid])
                    : 0.0f;

    const bool comp = (tid < 448);
    const int  row  = (tid < G4) ? tid : 0;
    float wv[HH];
    if (comp) {
        const float* w = launder(W_hh + row * HH);
        #pragma unroll
        for (int j = 0; j < HH / 4; ++j)
            *(float4*)&wv[4 * j] = ((const float4*)w)[j];
    }
    const float* pb = pre + (size_t)b * chSteps * G4;
    float preg = comp ? pb[row] : 0.0f;     // t=0 (bias already folded in)
    float* hout = (flags & 1) ? (h1out + ((size_t)b * TT + tbase) * HH) : nullptr;
    __syncthreads();

    #pragma unroll 1
    for (int t = 0; t < chSteps; ++t) {
        if (comp) {
            float pnext = (t + 1 < chSteps) ? pb[(size_t)(t + 1) * G4 + row] : 0.f;
            float va = hb[lane];
            float vb = hb[64 + lane];       // lanes >= 36 read 0-pad
            asm volatile("" : "+v"(va), "+v"(vb));
            float a0 = preg, a1 = 0.f;
            #pragma unroll
            for (int j = 0; j < 64; ++j) {
                float s = bcast(va, j);
                if (j & 1) a1 += s * wv[j]; else a0 += s * wv[j];
            }
            #pragma unroll
            for (int j = 0; j < 36; ++j) {
                float s = bcast(vb, j);
                if (j & 1) a1 += s * wv[64 + j]; else a0 += s * wv[64 + j];
            }
            gates[tid] = a0 + a1;
            preg = pnext;
        }
        __syncthreads();
        if (tid < HH) {
            float ri = gates[tid];
            float rf = gates[tid + HH];
            float rg = gates[tid + 2 * HH];
            float ro = gates[tid + 3 * HH];
            float cc = sigm(rf) * c_reg + sigm(ri) * tanh_fast(rg);
            c_reg = cc;
            float hv = sigm(ro) * tanh_fast(cc);
            hb[tid] = hv;
            if (flags & 1) hout[(size_t)t * HH + tid] = hv;
        }
        __syncthreads();
    }

    if (tid < HH) {          // persist chunk-boundary state
        st[b * 200 + tid]      = hb[tid];
        st[b * 200 + HH + tid] = c_reg;
    }
    if ((flags & 2) && tid < NCLS) {   // final FC (layer2, last chunk)
        float acc = b_fc[tid];
        #pragma unroll 4
        for (int j = 0; j < HH; ++j) acc += W_fc[tid * HH + j] * hb[j];
        out[b * NCLS + tid] = acc;
    }
}

extern "C" void kernel_launch(void* const* d_in, const int* in_sizes, int n_in,
                              void* d_out, int out_size, void* d_ws, size_t ws_size,
                              hipStream_t stream) {
    const float* x     = (const float*)d_in[0];
    const float* h0_1  = (const float*)d_in[1];
    const float* c0_1  = (const float*)d_in[2];
    const float* h0_2  = (const float*)d_in[3];
    const float* c0_2  = (const float*)d_in[4];
    const float* W_ih1 = (const float*)d_in[5];
    const float* W_hh1 = (const float*)d_in[6];
    const float* b1    = (const float*)d_in[7];
    const float* W_ih2 = (const float*)d_in[8];
    const float* W_hh2 = (const float*)d_in[9];
    const float* b2    = (const float*)d_in[10];
    const float* W_fc  = (const float*)d_in[11];
    const float* b_fc  = (const float*)d_in[12];
    float* out = (float*)d_out;

    char* ws = (char*)d_ws;
    const size_t h1_bytes = (size_t)BB * TT * HH * 4;   // 104.9 MB
    const size_t st_bytes = (size_t)BB * 200 * 4;       // 0.2 MB
    float* h1  = (float*)ws;
    float* st1 = (float*)(ws + h1_bytes);
    float* st2 = (float*)(ws + h1_bytes + st_bytes);
    float* pre = (float*)(ws + h1_bytes + 2 * st_bytes);

    // chunk size from remaining workspace (multiple of 64, >= 64)
    size_t avail = (ws_size > h1_bytes + 2 * st_bytes)
                     ? ws_size - h1_bytes - 2 * st_bytes : 0;
    int CH = (int)(avail / ((size_t)BB * G4 * 4));
    CH = (CH / 64) * 64;
    if (CH > TT) CH = TT;
    if (CH < 64) CH = 64;
    if (CH > 256) CH = 256;   // cap: launch-count vs buffer-size balance

    // layer 1
    for (int t0 = 0; t0 < TT; t0 += CH) {
        int ns = (TT - t0 < CH) ? (TT - t0) : CH;
        xproj<<<dim3(BB, ns / 64), 512, 0, stream>>>(x, W_ih1, b1, pre, t0, ns);
        lstm_rec<<<BB, 512, 0, stream>>>(pre, h0_1, c0_1, W_hh1, h1, st1,
                                         nullptr, nullptr, nullptr, t0, ns, 1);
    }
    // layer 2
    for (int t0 = 0; t0 < TT; t0 += CH) {
        int ns = (TT - t0 < CH) ? (TT - t0) : CH;
        int flags = (t0 + ns >= TT) ? 2 : 0;
        hproj<<<dim3(BB, ns / 64), 512, 0, stream>>>(h1, W_ih2, b2, pre, t0, ns);
        lstm_rec<<<BB, 512, 0, stream>>>(pre, h0_2, c0_2, W_hh2, nullptr, st2,
                                         W_fc, b_fc, out, t0, ns, flags);
    }
}